// Round 15
// baseline (132.308 us; speedup 1.0000x reference)
//
#include <hip/hip_runtime.h>
#include <stdint.h>

typedef __attribute__((ext_vector_type(8))) short bf16x8;
typedef __attribute__((ext_vector_type(4))) short bf16x4;
typedef __attribute__((ext_vector_type(4))) float f32x4;
typedef __attribute__((ext_vector_type(2))) unsigned int u32x2;
typedef __attribute__((ext_vector_type(4))) unsigned int u32x4;
typedef unsigned int u32;
typedef unsigned short u16;

#define S_LEN 2048
#define DMODEL 1024
#define HD 64

// ---------- helpers ----------

// fp32 -> bf16 round-to-nearest-even (finite inputs only)
static __device__ __forceinline__ u16 f2bf(float f) {
  u32 u = __builtin_bit_cast(u32, f);
  return (u16)((u + 0x7fffu + ((u >> 16) & 1u)) >> 16);
}

// pack 2 f32 -> 2 bf16 in one u32 (lo = a, hi = b)
static __device__ __forceinline__ u32 cvt_pk(float a, float b) {
  u32 r;
  asm("v_cvt_pk_bf16_f32 %0, %1, %2" : "=v"(r) : "v"(a), "v"(b));
  return r;
}

// async 16B global->LDS; lds dest must be wave-uniform (HW adds lane*16)
static __device__ __forceinline__ void gl_lds16(const u16* g, u16* l) {
  __builtin_amdgcn_global_load_lds((const __attribute__((address_space(1))) u32*)g,
                                   (__attribute__((address_space(3))) u32*)l, 16, 0, 0);
}

// LDS byte address of a __shared__ pointer (low 32 bits of generic addr)
static __device__ __forceinline__ u32 lds_addr(const void* p) {
  return (u32)(uint64_t)p;
}

// hardware transpose read: lane l gets column (l&15) of its group's 4x16 bf16 rows
static __device__ __forceinline__ bf16x4 tr16(u32 addr) {
  bf16x4 r;
  asm volatile("ds_read_b64_tr_b16 %0, %1" : "=v"(r) : "v"(addr));
  return r;
}

// ---------- kernel 1: fp32 -> bf16 convert (4 weight matrices only) ----------
__global__ __launch_bounds__(256) void convert_w(
    const float* __restrict__ wq, const float* __restrict__ wk,
    const float* __restrict__ wv, const float* __restrict__ wo,
    u16* __restrict__ dst) {
  size_t i = ((size_t)blockIdx.x * 256 + threadIdx.x) * 8;
  u32 wsel = (u32)((i >> 20) & 3u);
  const float* src = (wsel == 0) ? wq : (wsel == 1) ? wk : (wsel == 2) ? wv : wo;
  size_t off = i & 0xFFFFFu;
  float4 a = *(const float4*)(src + off);
  float4 b = *(const float4*)(src + off + 4);
  bf16x8 o;
  o[0] = (short)f2bf(a.x); o[1] = (short)f2bf(a.y);
  o[2] = (short)f2bf(a.z); o[3] = (short)f2bf(a.w);
  o[4] = (short)f2bf(b.x); o[5] = (short)f2bf(b.y);
  o[6] = (short)f2bf(b.z); o[7] = (short)f2bf(b.w);
  *(bf16x8*)(dst + i) = o;
}

// ---------- GEMM core (bf16 A)  Y tile = (A @ B^T + bias) * scale ----------
template <int OUT_BF16, int BN>
static __device__ __forceinline__ void gemm_core(
    const u16* __restrict__ A, const u16* __restrict__ Bm,
    const float* __restrict__ bias, void* __restrict__ Y, float scale,
    int bm, int bn, u16* As, u16* Bs) {
  const int tid = threadIdx.x;
  const int lane = tid & 63, w = tid >> 6;
  const int wm = w >> 1, wn = w & 1;
  const int g = lane >> 4, l15 = lane & 15;
  constexpr int NFR = BN / 64 * 2;

  f32x4 acc[4][NFR] = {};

  const int r0 = tid >> 2, k8 = (tid & 3) * 8;
  const int r1 = (tid + 256) >> 2;
  const size_t arow0 = (size_t)(bm * 128 + r0) * DMODEL + k8;
  const size_t arow1 = (size_t)(bm * 128 + r1) * DMODEL + k8;
  const size_t brow0 = (size_t)(bn * BN + r0) * DMODEL + k8;
  const size_t brow1 = (size_t)(bn * BN + r1) * DMODEL + k8;

  auto stage = [&](int buf, int kt) {
    const int kb = kt * 32;
    u16* asb = As + buf * 4096;
    u16* bsb = Bs + buf * (BN * 32);
    gl_lds16(A + arow0 + kb, asb + w * 512);
    gl_lds16(A + arow1 + kb, asb + w * 512 + 2048);
    gl_lds16(Bm + brow0 + kb, bsb + w * 512);
    if constexpr (BN == 128) gl_lds16(Bm + brow1 + kb, bsb + w * 512 + 2048);
  };

  stage(0, 0);
  __syncthreads();
  int cur = 0;
  for (int kt = 0; kt < 32; ++kt) {
    if (kt < 31) stage(cur ^ 1, kt + 1);
    const u16* as = As + cur * 4096;
    const u16* bs = Bs + cur * (BN * 32);
    bf16x8 a[4], b[NFR];
#pragma unroll
    for (int mi = 0; mi < 4; ++mi)
      a[mi] = *(const bf16x8*)&as[(wm * 64 + mi * 16 + l15) * 32 + g * 8];
#pragma unroll
    for (int ni = 0; ni < NFR; ++ni)
      b[ni] = *(const bf16x8*)&bs[(wn * (BN / 2) + ni * 16 + l15) * 32 + g * 8];
#pragma unroll
    for (int mi = 0; mi < 4; ++mi)
#pragma unroll
      for (int ni = 0; ni < NFR; ++ni)
        acc[mi][ni] = __builtin_amdgcn_mfma_f32_16x16x32_bf16(a[mi], b[ni], acc[mi][ni], 0, 0, 0);
    __syncthreads();
    cur ^= 1;
  }

#pragma unroll
  for (int ni = 0; ni < NFR; ++ni) {
    const int col = bn * BN + wn * (BN / 2) + ni * 16 + l15;
    const float bv = bias[col];
#pragma unroll
    for (int mi = 0; mi < 4; ++mi) {
      const int row0 = bm * 128 + wm * 64 + mi * 16 + g * 4;
#pragma unroll
      for (int r = 0; r < 4; ++r) {
        float v = (acc[mi][ni][r] + bv) * scale;
        if (OUT_BF16)
          ((u16*)Y)[(size_t)(row0 + r) * DMODEL + col] = f2bf(v);
        else
          ((float*)Y)[(size_t)(row0 + r) * DMODEL + col] = v;
      }
    }
  }
}

// ---------- fused Q/K/V projections with in-kernel f32->bf16 A conversion ----
// R12-proven 1-deep reg-staged A (T14) but with 128x64 tiles, grid 1536 = 6
// blocks/CU = 6 waves/SIMD (was 128x128, 768 blocks, 3/CU). qkv was latency-
// bound with everything idle (Mfma 16%, VALU 31%, HBM 12%, occ 25%) -- the
// occupancy lever, not deeper per-wave pipelining (R13's 2-deep unroll halved
// occupancy and regressed; R10's runtime-indexed version spilled, rule #20).
// LDS 24KB/block. Bijective XCD swizzle: 16 bn-blocks of a bm on one XCD.
__global__ __launch_bounds__(256) void qkv_gemm(
    const float* __restrict__ xq, const float* __restrict__ xk, const float* __restrict__ xv,
    const u16* __restrict__ W,
    const float* __restrict__ bq, const float* __restrict__ bk, const float* __restrict__ bv,
    u16* __restrict__ Qp, u16* __restrict__ Kpp, u16* __restrict__ Vpp, float qscale) {
  __shared__ u16 As[2 * 4096];   // 16KB: A tile 128x32 bf16, dbuf
  __shared__ u16 Bs[2 * 2048];   // 8KB:  B tile 64x32 bf16, dbuf
  const int sel = blockIdx.x >> 9;           // 512 blocks per sel
  const int bb = blockIdx.x & 511;
  const int bm = (bb & 7) * 4 + (bb >> 7);   // bijective XCD swizzle (8x16x4)
  const int bn = (bb >> 3) & 15;
  const float* A = (sel == 0) ? xq : (sel == 1) ? xk : xv;
  const u16* Bm = W + (size_t)sel * (1024 * 1024);
  const float* bias = (sel == 0) ? bq : (sel == 1) ? bk : bv;
  u16* Y = (sel == 0) ? Qp : (sel == 1) ? Kpp : Vpp;
  const float scale = (sel == 0) ? qscale : 1.0f;

  const int tid = threadIdx.x;
  const int lane = tid & 63, w = tid >> 6;
  const int wm = w >> 1, wn = w & 1;
  const int g = lane >> 4, l15 = lane & 15;

  f32x4 acc[4][2] = {};

  const int r0 = tid >> 2, k8 = (tid & 3) * 8;
  const int r1 = (tid + 256) >> 2;
  const size_t arow0 = (size_t)(bm * 128 + r0) * DMODEL + k8;
  const size_t arow1 = (size_t)(bm * 128 + r1) * DMODEL + k8;
  const size_t brow0 = (size_t)(bn * 64 + r0) * DMODEL + k8;   // r0 in [0,64)

  float4 af0, af1, af2, af3;  // in-flight A chunk (f32) -- named scalars
  auto loadA = [&](int kt) {
    const int kb = kt * 32;
    af0 = *(const float4*)(A + arow0 + kb);
    af1 = *(const float4*)(A + arow0 + kb + 4);
    af2 = *(const float4*)(A + arow1 + kb);
    af3 = *(const float4*)(A + arow1 + kb + 4);
  };
  auto writeA = [&](int buf) {
    u16* asb = As + buf * 4096;
    u32x4 p0 = {cvt_pk(af0.x, af0.y), cvt_pk(af0.z, af0.w),
                cvt_pk(af1.x, af1.y), cvt_pk(af1.z, af1.w)};
    u32x4 p1 = {cvt_pk(af2.x, af2.y), cvt_pk(af2.z, af2.w),
                cvt_pk(af3.x, af3.y), cvt_pk(af3.z, af3.w)};
    *(u32x4*)(asb + tid * 8) = p0;
    *(u32x4*)(asb + tid * 8 + 2048) = p1;
  };
  auto stageB = [&](int buf, int kt) {
    const int kb = kt * 32;
    u16* bsb = Bs + buf * 2048;
    gl_lds16(Bm + brow0 + kb, bsb + w * 512);  // 256 chunks = 64 rows x 4
  };

  loadA(0);
  stageB(0, 0);
  writeA(0);
  __syncthreads();
  int cur = 0;
  for (int kt = 0; kt < 32; ++kt) {
    if (kt < 31) {            // issue next-tile loads EARLY (latency under MFMAs)
      loadA(kt + 1);
      stageB(cur ^ 1, kt + 1);
    }
    const u16* as = As + cur * 4096;
    const u16* bs = Bs + cur * 2048;
    bf16x8 a[4], b[2];
#pragma unroll
    for (int mi = 0; mi < 4; ++mi)
      a[mi] = *(const bf16x8*)&as[(wm * 64 + mi * 16 + l15) * 32 + g * 8];
#pragma unroll
    for (int ni = 0; ni < 2; ++ni)
      b[ni] = *(const bf16x8*)&bs[(wn * 32 + ni * 16 + l15) * 32 + g * 8];
#pragma unroll
    for (int mi = 0; mi < 4; ++mi)
#pragma unroll
      for (int ni = 0; ni < 2; ++ni)
        acc[mi][ni] = __builtin_amdgcn_mfma_f32_16x16x32_bf16(a[mi], b[ni], acc[mi][ni], 0, 0, 0);
    if (kt < 31) writeA(cur ^ 1);  // cvt + ds_write LATE (T14)
    __syncthreads();
    cur ^= 1;
  }

#pragma unroll
  for (int ni = 0; ni < 2; ++ni) {
    const int col = bn * 64 + wn * 32 + ni * 16 + l15;
    const float bv = bias[col];
#pragma unroll
    for (int mi = 0; mi < 4; ++mi) {
      const int row0 = bm * 128 + wm * 64 + mi * 16 + g * 4;
#pragma unroll
      for (int r = 0; r < 4; ++r) {
        float v = (acc[mi][ni][r] + bv) * scale;
        ((u16*)Y)[(size_t)(row0 + r) * DMODEL + col] = f2bf(v);
      }
    }
  }
}

// Wo projection: 128x64 tiles, grid 512, XCD-swizzled.
__global__ __launch_bounds__(256) void wo_gemm(
    const u16* __restrict__ A, const u16* __restrict__ Bm,
    const float* __restrict__ bias, float* __restrict__ Y) {
  __shared__ u16 As[2 * 4096];
  __shared__ u16 Bs[2 * 2048];
  const int idx = blockIdx.x;
  const int bm = (idx & 7) * 4 + (idx >> 7);
  const int bn = (idx >> 3) & 15;
  gemm_core<0, 64>(A, Bm, bias, Y, 1.0f, bm, bn, As, Bs);
}

// ---------- kernel 3: flash attention, 8 waves x 32q, in-block kv-split ----------
// (R12 winner, unchanged: R7 structure + T1 XCD swizzle.)
__global__ __launch_bounds__(512, 4) void attn_fwd(
    const u16* __restrict__ Qp, const u16* __restrict__ Kp,
    const u16* __restrict__ Vp, u16* __restrict__ Op) {
  __shared__ u16 smem[32768];
  u16* Kl = smem;           // bytes [0,16384): [buf2][half2][kv32][64d], xor-swz rows
  u16* Vl = smem + 8192;    // bytes [16384,32768): [buf2][half2][dt4][sub2][p16][16] tr-subtiled
  // Pl at bytes [32768,65536): 16 regions (w*2+qb) of [q16][128B], xor-swz
  const int tid = threadIdx.x;
  const int lane = tid & 63, w = tid >> 6;   // w = 0..7
  const int g = lane >> 4, l15 = lane & 15;
  const int qs = w & 3, hf = w >> 2;         // q-sub, kv-half
  // T1 bijective XCD swizzle: xcd = bid&7 -> bh = xcd*4 + (bid>>7)
  const int xcd = blockIdx.x & 7;
  const int idx = blockIdx.x >> 3;           // 0..63
  const int bh = xcd * 4 + (idx >> 4);       // all 16 qt-blocks of a bh: same XCD
  const int qt = idx & 15;
  const int b = bh >> 4, h = bh & 15;
  const size_t rowbase = (size_t)b * S_LEN;
  const int hcol = h * HD;

  // Q fragments for both 16-q sub-blocks (B-operand: c=l15=q, k=8g+i)
  bf16x8 qf[2][2];
#pragma unroll
  for (int qb = 0; qb < 2; ++qb) {
    const int qrow = qt * 128 + qs * 32 + qb * 16 + l15;
    qf[qb][0] = *(const bf16x8*)(Qp + (rowbase + qrow) * DMODEL + hcol + g * 8);
    qf[qb][1] = *(const bf16x8*)(Qp + (rowbase + qrow) * DMODEL + hcol + 32 + g * 8);
  }

  f32x4 o[2][4] = {};        // o[qb][dt]: rows q=4g+r, col dt*16+l15 (partial: this kv-half)
  float lsum[2] = {0.0f, 0.0f};

  const u32 sbase = lds_addr(smem);

  // staging: 512 threads, 1 K chunk + 1 V chunk each (16B), covering both halves
  const int half_s = tid >> 8;
  const int kvs = (tid >> 3) & 31, slot = (tid & 7) ^ (kvs & 7);
  const size_t koff = (rowbase + half_s * 1024 + kvs) * (size_t)DMODEL + hcol + slot * 8;
  const int cc = tid & 255;
  const int hh = cc & 1, p = (cc >> 1) & 15, sub = (cc >> 5) & 1, dt0 = (cc >> 6) & 3;
  const int kvv = 8 * (p >> 2) + sub * 4 + (p & 3);
  const size_t voff = (rowbase + half_s * 1024 + kvv) * (size_t)DMODEL + hcol + dt0 * 16 + hh * 8;

  auto stage = [&](int buf, int it) {
    const size_t adv = (size_t)it * 32 * DMODEL;
    gl_lds16(Kp + koff + adv, Kl + buf * 4096 + w * 512);
    gl_lds16(Vp + voff + adv, Vl + buf * 4096 + w * 512);
  };

  stage(0, 0);
  __syncthreads();
  int cur = 0;
  for (int it = 0; it < 32; ++it) {
    if (it < 31) stage(cur ^ 1, it + 1);
    const char* kb = (const char*)smem + cur * 8192 + hf * 4096;
    const u32 vbb = sbase + 16384 + (u32)(cur * 8192 + hf * 4096);
    const u32 pswz = (u32)((l15 & 7) << 4);

    // ---- S^T: s[qb][t][r] = score(kv_local = t*16+4g+r, q=l15); K read once ----
    f32x4 s[2][2];
    __builtin_amdgcn_s_setprio(1);
#pragma unroll
    for (int t = 0; t < 2; ++t) {
      const int kvl = t * 16 + l15;
      const u32 swz = (u32)((kvl & 7) << 4);
      bf16x8 k0 = *(const bf16x8*)(kb + (((u32)(kvl * 128 + g * 16)) ^ swz));
      bf16x8 k1 = *(const bf16x8*)(kb + (((u32)(kvl * 128 + 64 + g * 16)) ^ swz));
      f32x4 z = {};
      s[0][t] = __builtin_amdgcn_mfma_f32_16x16x32_bf16(
          k1, qf[0][1], __builtin_amdgcn_mfma_f32_16x16x32_bf16(k0, qf[0][0], z, 0, 0, 0), 0, 0, 0);
      s[1][t] = __builtin_amdgcn_mfma_f32_16x16x32_bf16(
          k1, qf[1][1], __builtin_amdgcn_mfma_f32_16x16x32_bf16(k0, qf[1][0], z, 0, 0, 0), 0, 0, 0);
    }
    __builtin_amdgcn_s_setprio(0);

    // ---- static softmax + P write per sub-block ----
#pragma unroll
    for (int qb = 0; qb < 2; ++qb) {
      const u32 pb = (u32)(32768 + (w * 2 + qb) * 2048 + l15 * 128);
      float psum = 0.0f;
#pragma unroll
      for (int t = 0; t < 2; ++t) {
        float e0 = __builtin_amdgcn_exp2f(s[qb][t][0]);
        float e1 = __builtin_amdgcn_exp2f(s[qb][t][1]);
        float e2 = __builtin_amdgcn_exp2f(s[qb][t][2]);
        float e3 = __builtin_amdgcn_exp2f(s[qb][t][3]);
        psum += (e0 + e1) + (e2 + e3);
        u32x2 pk = {cvt_pk(e0, e1), cvt_pk(e2, e3)};
        *(u32x2*)((char*)smem + ((pb + (u32)(t * 32 + g * 8)) ^ pswz)) = pk;
      }
      lsum[qb] += psum;
    }

    // ---- PV: P A-frags (both qb) + shared V tr-frags, wait, 8 mfma ----
    bf16x8 pf[2];
    bf16x4 tv[4][2];
#pragma unroll
    for (int qb = 0; qb < 2; ++qb) {
      const u32 pb = (u32)(32768 + (w * 2 + qb) * 2048 + l15 * 128);
      pf[qb] = *(const bf16x8*)((const char*)smem + ((pb + (u32)(g * 16)) ^ pswz));
    }
#pragma unroll
    for (int dt = 0; dt < 4; ++dt)
#pragma unroll
      for (int sb = 0; sb < 2; ++sb)
        tv[dt][sb] = tr16(vbb + (u32)((dt * 2 + sb) * 512 + lane * 8));
    asm volatile("s_waitcnt lgkmcnt(0)" ::: "memory");   // rule 18
    __builtin_amdgcn_sched_barrier(0);
    __builtin_amdgcn_s_setprio(1);
#pragma unroll
    for (int dt = 0; dt < 4; ++dt) {
      bf16x8 vf;
      vf[0] = tv[dt][0][0]; vf[1] = tv[dt][0][1];
      vf[2] = tv[dt][0][2]; vf[3] = tv[dt][0][3];
      vf[4] = tv[dt][1][0]; vf[5] = tv[dt][1][1];
      vf[6] = tv[dt][1][2]; vf[7] = tv[dt][1][3];
      o[0][dt] = __builtin_amdgcn_mfma_f32_16x16x32_bf16(pf[0], vf, o[0][dt], 0, 0, 0);
      o[1][dt] = __builtin_amdgcn_mfma_f32_16x16x32_bf16(pf[1], vf, o[1][dt], 0, 0, 0);
    }
    __builtin_amdgcn_s_setprio(0);
    __syncthreads();
    cur ^= 1;
  }

  // ---- epilogue: combine kv-halves (pure addition, static softmax) ----
  float ls[2];
#pragma unroll
  for (int qb = 0; qb < 2; ++qb) {
    float v = lsum[qb];
    v += __shfl_xor(v, 16);
    v += __shfl_xor(v, 32);
    ls[qb] = v;
  }
  if (w >= 4) {               // half-1 waves dump partials
    char* ob = (char*)smem + (w - 4) * 8192 + lane * 16;
#pragma unroll
    for (int qb = 0; qb < 2; ++qb)
#pragma unroll
      for (int dt = 0; dt < 4; ++dt)
        *(f32x4*)(ob + (qb * 4 + dt) * 1024) = o[qb][dt];
    float2 lw = {ls[0], ls[1]};
    *(float2*)((char*)smem + 32768 + (w - 4) * 512 + lane * 8) = lw;
  }
  __syncthreads();
  if (w < 4) {                // half-0 waves combine, normalize, store
    const char* ob = (const char*)smem + w * 8192 + lane * 16;
#pragma unroll
    for (int qb = 0; qb < 2; ++qb)
#pragma unroll
      for (int dt = 0; dt < 4; ++dt)
        o[qb][dt] += *(const f32x4*)(ob + (qb * 4 + dt) * 1024);
    const float2 lp = *(const float2*)((const char*)smem + 32768 + w * 512 + lane * 8);
    ls[0] += lp.x;
    ls[1] += lp.y;
#pragma unroll
    for (int qb = 0; qb < 2; ++qb) {
      const float linv = 1.0f / ls[qb];
      const float li0 = __shfl(linv, g * 4 + 0);
      const float li1 = __shfl(linv, g * 4 + 1);
      const float li2 = __shfl(linv, g * 4 + 2);
      const float li3 = __shfl(linv, g * 4 + 3);
      const float li[4] = {li0, li1, li2, li3};
#pragma unroll
      for (int dt = 0; dt < 4; ++dt)
#pragma unroll
        for (int r = 0; r < 4; ++r) {
          const int qr = qt * 128 + w * 32 + qb * 16 + g * 4 + r;
          Op[(rowbase + qr) * DMODEL + hcol + dt * 16 + l15] = f2bf(o[qb][dt][r] * li[r]);
        }
    }
  }
}

// ---------- host ----------
extern "C" void kernel_launch(void* const* d_in, const int* in_sizes, int n_in,
                              void* d_out, int out_size, void* d_ws, size_t ws_size,
                              hipStream_t stream) {
  const float* xq = (const float*)d_in[0];
  const float* xk = (const float*)d_in[1];
  const float* xv = (const float*)d_in[2];
  const float* Wq = (const float*)d_in[3];
  const float* bq = (const float*)d_in[4];
  const float* Wk = (const float*)d_in[5];
  const float* bk = (const float*)d_in[6];
  const float* Wv = (const float*)d_in[7];
  const float* bv = (const float*)d_in[8];
  const float* Wo = (const float*)d_in[9];
  const float* bo = (const float*)d_in[10];

  u16* ws = (u16*)d_ws;
  const size_t MB4 = 4096ull * 1024ull;  // 4M bf16 elems
  u16* WQb = ws + 3 * MB4;               // converted weights (4 x 1M)
  u16* Qp = ws + 4 * MB4;                // projected Q (pre-scaled by 0.125*log2e)
  u16* Kpp = ws + 5 * MB4;
  u16* Vpp = ws + 6 * MB4;
  u16* Opp = ws + 7 * MB4;               // attention output (bf16)

  convert_w<<<2048, 256, 0, stream>>>(Wq, Wk, Wv, Wo, WQb);

  const float qscale = 0.125f * 1.44269504088896340736f;  // 1/sqrt(hd) * log2(e)
  qkv_gemm<<<1536, 256, 0, stream>>>(xq, xk, xv, WQb, bq, bk, bv, Qp, Kpp, Vpp, qscale);

  attn_fwd<<<512, 512, 0, stream>>>(Qp, Kpp, Vpp, Opp);

  wo_gemm<<<512, 256, 0, stream>>>(Opp, WQb + 3 * 1024 * 1024, bo, (float*)d_out);
}

// Round 16
// 113.333 us; speedup vs baseline: 1.1674x; 1.1674x over previous
//
#include <hip/hip_runtime.h>
#include <stdint.h>

typedef __attribute__((ext_vector_type(8))) short bf16x8;
typedef __attribute__((ext_vector_type(4))) short bf16x4;
typedef __attribute__((ext_vector_type(4))) float f32x4;
typedef __attribute__((ext_vector_type(2))) unsigned int u32x2;
typedef __attribute__((ext_vector_type(4))) unsigned int u32x4;
typedef unsigned int u32;
typedef unsigned short u16;

#define S_LEN 2048
#define DMODEL 1024
#define HD 64

// ---------- helpers ----------

// fp32 -> bf16 round-to-nearest-even (finite inputs only)
static __device__ __forceinline__ u16 f2bf(float f) {
  u32 u = __builtin_bit_cast(u32, f);
  return (u16)((u + 0x7fffu + ((u >> 16) & 1u)) >> 16);
}

// pack 2 f32 -> 2 bf16 in one u32 (lo = a, hi = b)
static __device__ __forceinline__ u32 cvt_pk(float a, float b) {
  u32 r;
  asm("v_cvt_pk_bf16_f32 %0, %1, %2" : "=v"(r) : "v"(a), "v"(b));
  return r;
}

// async 16B global->LDS; lds dest must be wave-uniform (HW adds lane*16)
static __device__ __forceinline__ void gl_lds16(const u16* g, u16* l) {
  __builtin_amdgcn_global_load_lds((const __attribute__((address_space(1))) u32*)g,
                                   (__attribute__((address_space(3))) u32*)l, 16, 0, 0);
}

// LDS byte address of a __shared__ pointer (low 32 bits of generic addr)
static __device__ __forceinline__ u32 lds_addr(const void* p) {
  return (u32)(uint64_t)p;
}

// hardware transpose read: lane l gets column (l&15) of its group's 4x16 bf16 rows
static __device__ __forceinline__ bf16x4 tr16(u32 addr) {
  bf16x4 r;
  asm volatile("ds_read_b64_tr_b16 %0, %1" : "=v"(r) : "v"(addr));
  return r;
}

// ---------- kernel 1: fp32 -> bf16 convert (4 weight matrices only) ----------
__global__ __launch_bounds__(256) void convert_w(
    const float* __restrict__ wq, const float* __restrict__ wk,
    const float* __restrict__ wv, const float* __restrict__ wo,
    u16* __restrict__ dst) {
  size_t i = ((size_t)blockIdx.x * 256 + threadIdx.x) * 8;
  u32 wsel = (u32)((i >> 20) & 3u);
  const float* src = (wsel == 0) ? wq : (wsel == 1) ? wk : (wsel == 2) ? wv : wo;
  size_t off = i & 0xFFFFFu;
  float4 a = *(const float4*)(src + off);
  float4 b = *(const float4*)(src + off + 4);
  bf16x8 o;
  o[0] = (short)f2bf(a.x); o[1] = (short)f2bf(a.y);
  o[2] = (short)f2bf(a.z); o[3] = (short)f2bf(a.w);
  o[4] = (short)f2bf(b.x); o[5] = (short)f2bf(b.y);
  o[6] = (short)f2bf(b.z); o[7] = (short)f2bf(b.w);
  *(bf16x8*)(dst + i) = o;
}

// ---------- GEMM core (bf16 A)  Y tile = (A @ B^T + bias) * scale ----------
template <int OUT_BF16, int BN>
static __device__ __forceinline__ void gemm_core(
    const u16* __restrict__ A, const u16* __restrict__ Bm,
    const float* __restrict__ bias, void* __restrict__ Y, float scale,
    int bm, int bn, u16* As, u16* Bs) {
  const int tid = threadIdx.x;
  const int lane = tid & 63, w = tid >> 6;
  const int wm = w >> 1, wn = w & 1;
  const int g = lane >> 4, l15 = lane & 15;
  constexpr int NFR = BN / 64 * 2;

  f32x4 acc[4][NFR] = {};

  const int r0 = tid >> 2, k8 = (tid & 3) * 8;
  const int r1 = (tid + 256) >> 2;
  const size_t arow0 = (size_t)(bm * 128 + r0) * DMODEL + k8;
  const size_t arow1 = (size_t)(bm * 128 + r1) * DMODEL + k8;
  const size_t brow0 = (size_t)(bn * BN + r0) * DMODEL + k8;
  const size_t brow1 = (size_t)(bn * BN + r1) * DMODEL + k8;

  auto stage = [&](int buf, int kt) {
    const int kb = kt * 32;
    u16* asb = As + buf * 4096;
    u16* bsb = Bs + buf * (BN * 32);
    gl_lds16(A + arow0 + kb, asb + w * 512);
    gl_lds16(A + arow1 + kb, asb + w * 512 + 2048);
    gl_lds16(Bm + brow0 + kb, bsb + w * 512);
    if constexpr (BN == 128) gl_lds16(Bm + brow1 + kb, bsb + w * 512 + 2048);
  };

  stage(0, 0);
  __syncthreads();
  int cur = 0;
  for (int kt = 0; kt < 32; ++kt) {
    if (kt < 31) stage(cur ^ 1, kt + 1);
    const u16* as = As + cur * 4096;
    const u16* bs = Bs + cur * (BN * 32);
    bf16x8 a[4], b[NFR];
#pragma unroll
    for (int mi = 0; mi < 4; ++mi)
      a[mi] = *(const bf16x8*)&as[(wm * 64 + mi * 16 + l15) * 32 + g * 8];
#pragma unroll
    for (int ni = 0; ni < NFR; ++ni)
      b[ni] = *(const bf16x8*)&bs[(wn * (BN / 2) + ni * 16 + l15) * 32 + g * 8];
#pragma unroll
    for (int mi = 0; mi < 4; ++mi)
#pragma unroll
      for (int ni = 0; ni < NFR; ++ni)
        acc[mi][ni] = __builtin_amdgcn_mfma_f32_16x16x32_bf16(a[mi], b[ni], acc[mi][ni], 0, 0, 0);
    __syncthreads();
    cur ^= 1;
  }

#pragma unroll
  for (int ni = 0; ni < NFR; ++ni) {
    const int col = bn * BN + wn * (BN / 2) + ni * 16 + l15;
    const float bv = bias[col];
#pragma unroll
    for (int mi = 0; mi < 4; ++mi) {
      const int row0 = bm * 128 + wm * 64 + mi * 16 + g * 4;
#pragma unroll
      for (int r = 0; r < 4; ++r) {
        float v = (acc[mi][ni][r] + bv) * scale;
        if (OUT_BF16)
          ((u16*)Y)[(size_t)(row0 + r) * DMODEL + col] = f2bf(v);
        else
          ((float*)Y)[(size_t)(row0 + r) * DMODEL + col] = v;
      }
    }
  }
}

// ---------- fused Q/K/V projections with in-kernel f32->bf16 A conversion ----
// 128x128 tile (R12's proven shape/intensity) but 8 WAVES (512 threads): each
// wave computes 64x32 (acc[4][2]); per-block staging traffic identical to R12,
// per-thread staging halves, waves/SIMD 3 -> 6. (R13 deep-pipeline halved
// occupancy: regressed. R14 smaller tile halved intensity: regressed. This
// keeps intensity and doubles TLP.) 1-deep reg-staged A (T14), B via
// global_load_lds, T1 bijective XCD swizzle.
__global__ __launch_bounds__(512, 6) void qkv_gemm(
    const float* __restrict__ xq, const float* __restrict__ xk, const float* __restrict__ xv,
    const u16* __restrict__ W,
    const float* __restrict__ bq, const float* __restrict__ bk, const float* __restrict__ bv,
    u16* __restrict__ Qp, u16* __restrict__ Kpp, u16* __restrict__ Vpp, float qscale) {
  __shared__ u16 As[2 * 4096];   // 16KB: A tile 128x32 bf16, dbuf
  __shared__ u16 Bs[2 * 4096];   // 16KB: B tile 128x32 bf16, dbuf
  const int sel = blockIdx.x >> 8;
  const int bb = blockIdx.x & 255;
  const int bm = (bb & 7) * 4 + (bb >> 6);   // bijective XCD swizzle
  const int bn = (bb >> 3) & 7;
  const float* A = (sel == 0) ? xq : (sel == 1) ? xk : xv;
  const u16* Bm = W + (size_t)sel * (1024 * 1024);
  const float* bias = (sel == 0) ? bq : (sel == 1) ? bk : bv;
  u16* Y = (sel == 0) ? Qp : (sel == 1) ? Kpp : Vpp;
  const float scale = (sel == 0) ? qscale : 1.0f;

  const int tid = threadIdx.x;           // 0..511
  const int lane = tid & 63, w = tid >> 6;   // w = 0..7
  const int wm = w >> 2, wn = w & 3;     // wave tile: rows wm*64, cols wn*32
  const int g = lane >> 4, l15 = lane & 15;

  f32x4 acc[4][2] = {};

  const int r0 = tid >> 2, k8 = (tid & 3) * 8;   // A: row r0, f32s k8..k8+7
  const size_t arow0 = (size_t)(bm * 128 + r0) * DMODEL + k8;
  const size_t brow0 = (size_t)(bn * 128 + r0) * DMODEL + k8;  // B chunk = tid

  float4 af0, af1;  // in-flight A chunk (8 f32) -- named scalars
  auto loadA = [&](int kt) {
    const int kb = kt * 32;
    af0 = *(const float4*)(A + arow0 + kb);
    af1 = *(const float4*)(A + arow0 + kb + 4);
  };
  auto writeA = [&](int buf) {
    u16* asb = As + buf * 4096;
    u32x4 p0 = {cvt_pk(af0.x, af0.y), cvt_pk(af0.z, af0.w),
                cvt_pk(af1.x, af1.y), cvt_pk(af1.z, af1.w)};
    *(u32x4*)(asb + tid * 8) = p0;   // row r0, elems k8..k8+7 (= tid*8)
  };
  auto stageB = [&](int buf, int kt) {
    const int kb = kt * 32;
    u16* bsb = Bs + buf * 4096;
    gl_lds16(Bm + brow0 + kb, bsb + w * 512);  // 512 chunks, 1/thread
  };

  loadA(0);
  stageB(0, 0);
  writeA(0);
  __syncthreads();
  int cur = 0;
  for (int kt = 0; kt < 32; ++kt) {
    if (kt < 31) {            // issue next-tile loads EARLY (latency under MFMAs)
      loadA(kt + 1);
      stageB(cur ^ 1, kt + 1);
    }
    const u16* as = As + cur * 4096;
    const u16* bs = Bs + cur * 4096;
    bf16x8 a[4], b[2];
#pragma unroll
    for (int mi = 0; mi < 4; ++mi)
      a[mi] = *(const bf16x8*)&as[(wm * 64 + mi * 16 + l15) * 32 + g * 8];
#pragma unroll
    for (int ni = 0; ni < 2; ++ni)
      b[ni] = *(const bf16x8*)&bs[(wn * 32 + ni * 16 + l15) * 32 + g * 8];
#pragma unroll
    for (int mi = 0; mi < 4; ++mi)
#pragma unroll
      for (int ni = 0; ni < 2; ++ni)
        acc[mi][ni] = __builtin_amdgcn_mfma_f32_16x16x32_bf16(a[mi], b[ni], acc[mi][ni], 0, 0, 0);
    if (kt < 31) writeA(cur ^ 1);  // cvt + ds_write LATE (T14)
    __syncthreads();
    cur ^= 1;
  }

#pragma unroll
  for (int ni = 0; ni < 2; ++ni) {
    const int col = bn * 128 + wn * 32 + ni * 16 + l15;
    const float bv = bias[col];
#pragma unroll
    for (int mi = 0; mi < 4; ++mi) {
      const int row0 = bm * 128 + wm * 64 + mi * 16 + g * 4;
#pragma unroll
      for (int r = 0; r < 4; ++r) {
        float v = (acc[mi][ni][r] + bv) * scale;
        ((u16*)Y)[(size_t)(row0 + r) * DMODEL + col] = f2bf(v);
      }
    }
  }
}

// Wo projection: 128x64 tiles, grid 512, XCD-swizzled.
__global__ __launch_bounds__(256) void wo_gemm(
    const u16* __restrict__ A, const u16* __restrict__ Bm,
    const float* __restrict__ bias, float* __restrict__ Y) {
  __shared__ u16 As[2 * 4096];
  __shared__ u16 Bs[2 * 2048];
  const int idx = blockIdx.x;
  const int bm = (idx & 7) * 4 + (idx >> 7);
  const int bn = (idx >> 3) & 15;
  gemm_core<0, 64>(A, Bm, bias, Y, 1.0f, bm, bn, As, Bs);
}

// ---------- kernel 3: flash attention, 8 waves x 32q, in-block kv-split ----------
// (R12 winner, unchanged: R7 structure + T1 XCD swizzle.)
__global__ __launch_bounds__(512, 4) void attn_fwd(
    const u16* __restrict__ Qp, const u16* __restrict__ Kp,
    const u16* __restrict__ Vp, u16* __restrict__ Op) {
  __shared__ u16 smem[32768];
  u16* Kl = smem;           // bytes [0,16384): [buf2][half2][kv32][64d], xor-swz rows
  u16* Vl = smem + 8192;    // bytes [16384,32768): [buf2][half2][dt4][sub2][p16][16] tr-subtiled
  // Pl at bytes [32768,65536): 16 regions (w*2+qb) of [q16][128B], xor-swz
  const int tid = threadIdx.x;
  const int lane = tid & 63, w = tid >> 6;   // w = 0..7
  const int g = lane >> 4, l15 = lane & 15;
  const int qs = w & 3, hf = w >> 2;         // q-sub, kv-half
  // T1 bijective XCD swizzle: xcd = bid&7 -> bh = xcd*4 + (bid>>7)
  const int xcd = blockIdx.x & 7;
  const int idx = blockIdx.x >> 3;           // 0..63
  const int bh = xcd * 4 + (idx >> 4);       // all 16 qt-blocks of a bh: same XCD
  const int qt = idx & 15;
  const int b = bh >> 4, h = bh & 15;
  const size_t rowbase = (size_t)b * S_LEN;
  const int hcol = h * HD;

  // Q fragments for both 16-q sub-blocks (B-operand: c=l15=q, k=8g+i)
  bf16x8 qf[2][2];
#pragma unroll
  for (int qb = 0; qb < 2; ++qb) {
    const int qrow = qt * 128 + qs * 32 + qb * 16 + l15;
    qf[qb][0] = *(const bf16x8*)(Qp + (rowbase + qrow) * DMODEL + hcol + g * 8);
    qf[qb][1] = *(const bf16x8*)(Qp + (rowbase + qrow) * DMODEL + hcol + 32 + g * 8);
  }

  f32x4 o[2][4] = {};        // o[qb][dt]: rows q=4g+r, col dt*16+l15 (partial: this kv-half)
  float lsum[2] = {0.0f, 0.0f};

  const u32 sbase = lds_addr(smem);

  // staging: 512 threads, 1 K chunk + 1 V chunk each (16B), covering both halves
  const int half_s = tid >> 8;
  const int kvs = (tid >> 3) & 31, slot = (tid & 7) ^ (kvs & 7);
  const size_t koff = (rowbase + half_s * 1024 + kvs) * (size_t)DMODEL + hcol + slot * 8;
  const int cc = tid & 255;
  const int hh = cc & 1, p = (cc >> 1) & 15, sub = (cc >> 5) & 1, dt0 = (cc >> 6) & 3;
  const int kvv = 8 * (p >> 2) + sub * 4 + (p & 3);
  const size_t voff = (rowbase + half_s * 1024 + kvv) * (size_t)DMODEL + hcol + dt0 * 16 + hh * 8;

  auto stage = [&](int buf, int it) {
    const size_t adv = (size_t)it * 32 * DMODEL;
    gl_lds16(Kp + koff + adv, Kl + buf * 4096 + w * 512);
    gl_lds16(Vp + voff + adv, Vl + buf * 4096 + w * 512);
  };

  stage(0, 0);
  __syncthreads();
  int cur = 0;
  for (int it = 0; it < 32; ++it) {
    if (it < 31) stage(cur ^ 1, it + 1);
    const char* kb = (const char*)smem + cur * 8192 + hf * 4096;
    const u32 vbb = sbase + 16384 + (u32)(cur * 8192 + hf * 4096);
    const u32 pswz = (u32)((l15 & 7) << 4);

    // ---- S^T: s[qb][t][r] = score(kv_local = t*16+4g+r, q=l15); K read once ----
    f32x4 s[2][2];
    __builtin_amdgcn_s_setprio(1);
#pragma unroll
    for (int t = 0; t < 2; ++t) {
      const int kvl = t * 16 + l15;
      const u32 swz = (u32)((kvl & 7) << 4);
      bf16x8 k0 = *(const bf16x8*)(kb + (((u32)(kvl * 128 + g * 16)) ^ swz));
      bf16x8 k1 = *(const bf16x8*)(kb + (((u32)(kvl * 128 + 64 + g * 16)) ^ swz));
      f32x4 z = {};
      s[0][t] = __builtin_amdgcn_mfma_f32_16x16x32_bf16(
          k1, qf[0][1], __builtin_amdgcn_mfma_f32_16x16x32_bf16(k0, qf[0][0], z, 0, 0, 0), 0, 0, 0);
      s[1][t] = __builtin_amdgcn_mfma_f32_16x16x32_bf16(
          k1, qf[1][1], __builtin_amdgcn_mfma_f32_16x16x32_bf16(k0, qf[1][0], z, 0, 0, 0), 0, 0, 0);
    }
    __builtin_amdgcn_s_setprio(0);

    // ---- static softmax + P write per sub-block ----
#pragma unroll
    for (int qb = 0; qb < 2; ++qb) {
      const u32 pb = (u32)(32768 + (w * 2 + qb) * 2048 + l15 * 128);
      float psum = 0.0f;
#pragma unroll
      for (int t = 0; t < 2; ++t) {
        float e0 = __builtin_amdgcn_exp2f(s[qb][t][0]);
        float e1 = __builtin_amdgcn_exp2f(s[qb][t][1]);
        float e2 = __builtin_amdgcn_exp2f(s[qb][t][2]);
        float e3 = __builtin_amdgcn_exp2f(s[qb][t][3]);
        psum += (e0 + e1) + (e2 + e3);
        u32x2 pk = {cvt_pk(e0, e1), cvt_pk(e2, e3)};
        *(u32x2*)((char*)smem + ((pb + (u32)(t * 32 + g * 8)) ^ pswz)) = pk;
      }
      lsum[qb] += psum;
    }

    // ---- PV: P A-frags (both qb) + shared V tr-frags, wait, 8 mfma ----
    bf16x8 pf[2];
    bf16x4 tv[4][2];
#pragma unroll
    for (int qb = 0; qb < 2; ++qb) {
      const u32 pb = (u32)(32768 + (w * 2 + qb) * 2048 + l15 * 128);
      pf[qb] = *(const bf16x8*)((const char*)smem + ((pb + (u32)(g * 16)) ^ pswz));
    }
#pragma unroll
    for (int dt = 0; dt < 4; ++dt)
#pragma unroll
      for (int sb = 0; sb < 2; ++sb)
        tv[dt][sb] = tr16(vbb + (u32)((dt * 2 + sb) * 512 + lane * 8));
    asm volatile("s_waitcnt lgkmcnt(0)" ::: "memory");   // rule 18
    __builtin_amdgcn_sched_barrier(0);
    __builtin_amdgcn_s_setprio(1);
#pragma unroll
    for (int dt = 0; dt < 4; ++dt) {
      bf16x8 vf;
      vf[0] = tv[dt][0][0]; vf[1] = tv[dt][0][1];
      vf[2] = tv[dt][0][2]; vf[3] = tv[dt][0][3];
      vf[4] = tv[dt][1][0]; vf[5] = tv[dt][1][1];
      vf[6] = tv[dt][1][2]; vf[7] = tv[dt][1][3];
      o[0][dt] = __builtin_amdgcn_mfma_f32_16x16x32_bf16(pf[0], vf, o[0][dt], 0, 0, 0);
      o[1][dt] = __builtin_amdgcn_mfma_f32_16x16x32_bf16(pf[1], vf, o[1][dt], 0, 0, 0);
    }
    __builtin_amdgcn_s_setprio(0);
    __syncthreads();
    cur ^= 1;
  }

  // ---- epilogue: combine kv-halves (pure addition, static softmax) ----
  float ls[2];
#pragma unroll
  for (int qb = 0; qb < 2; ++qb) {
    float v = lsum[qb];
    v += __shfl_xor(v, 16);
    v += __shfl_xor(v, 32);
    ls[qb] = v;
  }
  if (w >= 4) {               // half-1 waves dump partials
    char* ob = (char*)smem + (w - 4) * 8192 + lane * 16;
#pragma unroll
    for (int qb = 0; qb < 2; ++qb)
#pragma unroll
      for (int dt = 0; dt < 4; ++dt)
        *(f32x4*)(ob + (qb * 4 + dt) * 1024) = o[qb][dt];
    float2 lw = {ls[0], ls[1]};
    *(float2*)((char*)smem + 32768 + (w - 4) * 512 + lane * 8) = lw;
  }
  __syncthreads();
  if (w < 4) {                // half-0 waves combine, normalize, store
    const char* ob = (const char*)smem + w * 8192 + lane * 16;
#pragma unroll
    for (int qb = 0; qb < 2; ++qb)
#pragma unroll
      for (int dt = 0; dt < 4; ++dt)
        o[qb][dt] += *(const f32x4*)(ob + (qb * 4 + dt) * 1024);
    const float2 lp = *(const float2*)((const char*)smem + 32768 + w * 512 + lane * 8);
    ls[0] += lp.x;
    ls[1] += lp.y;
#pragma unroll
    for (int qb = 0; qb < 2; ++qb) {
      const float linv = 1.0f / ls[qb];
      const float li0 = __shfl(linv, g * 4 + 0);
      const float li1 = __shfl(linv, g * 4 + 1);
      const float li2 = __shfl(linv, g * 4 + 2);
      const float li3 = __shfl(linv, g * 4 + 3);
      const float li[4] = {li0, li1, li2, li3};
#pragma unroll
      for (int dt = 0; dt < 4; ++dt)
#pragma unroll
        for (int r = 0; r < 4; ++r) {
          const int qr = qt * 128 + w * 32 + qb * 16 + g * 4 + r;
          Op[(rowbase + qr) * DMODEL + hcol + dt * 16 + l15] = f2bf(o[qb][dt][r] * li[r]);
        }
    }
  }
}

// ---------- host ----------
extern "C" void kernel_launch(void* const* d_in, const int* in_sizes, int n_in,
                              void* d_out, int out_size, void* d_ws, size_t ws_size,
                              hipStream_t stream) {
  const float* xq = (const float*)d_in[0];
  const float* xk = (const float*)d_in[1];
  const float* xv = (const float*)d_in[2];
  const float* Wq = (const float*)d_in[3];
  const float* bq = (const float*)d_in[4];
  const float* Wk = (const float*)d_in[5];
  const float* bk = (const float*)d_in[6];
  const float* Wv = (const float*)d_in[7];
  const float* bv = (const float*)d_in[8];
  const float* Wo = (const float*)d_in[9];
  const float* bo = (const float*)d_in[10];

  u16* ws = (u16*)d_ws;
  const size_t MB4 = 4096ull * 1024ull;  // 4M bf16 elems
  u16* WQb = ws + 3 * MB4;               // converted weights (4 x 1M)
  u16* Qp = ws + 4 * MB4;                // projected Q (pre-scaled by 0.125*log2e)
  u16* Kpp = ws + 5 * MB4;
  u16* Vpp = ws + 6 * MB4;
  u16* Opp = ws + 7 * MB4;               // attention output (bf16)

  convert_w<<<2048, 256, 0, stream>>>(Wq, Wk, Wv, Wo, WQb);

  const float qscale = 0.125f * 1.44269504088896340736f;  // 1/sqrt(hd) * log2(e)
  qkv_gemm<<<768, 512, 0, stream>>>(xq, xk, xv, WQb, bq, bk, bv, Qp, Kpp, Vpp, qscale);

  attn_fwd<<<512, 512, 0, stream>>>(Qp, Kpp, Vpp, Opp);

  wo_gemm<<<512, 256, 0, stream>>>(Opp, WQb + 3 * 1024 * 1024, bo, (float*)d_out);
}